// Round 12
// baseline (2089.036 us; speedup 1.0000x reference)
//
#include <hip/hip_runtime.h>
#include <hip/hip_bf16.h>

#define BATCH 32
#define E 256
#define V 32000
#define NSTEP 128
#define M_TOTAL (BATCH * NSTEP)   // 4096
#define BM 128
#define BN2 128
#define NBT (V / BN2)             // 250 b-tiles
#define NGRP 8                    // bn groups (== XCDs)
#define L2E 1.4426950408889634f
#define TREP 16                   // traj measurement repeats
#define GREP 16                   // gemm measurement repeats

typedef __attribute__((ext_vector_type(4))) float f32x4;
typedef __attribute__((ext_vector_type(2))) float f32x2;
typedef __attribute__((ext_vector_type(8))) short s16x8;
typedef __attribute__((ext_vector_type(4))) unsigned int u32x4;

static __device__ __forceinline__ short f2bf(float v) {
    __hip_bfloat16 h = __float2bfloat16(v);
    return *reinterpret_cast<short*>(&h);
}

static __device__ __forceinline__ unsigned char f2fp8(float v) {
    int p = __builtin_amdgcn_cvt_pk_fp8_f32(v, v, 0, false);
    return (unsigned char)(p & 0xff);
}
template<bool HI>
static __device__ __forceinline__ f32x2 fp8x2_to_f32(unsigned int x) {
    return __builtin_amdgcn_cvt_pk_f32_fp8((int)x, HI);
}

// frag-major byte position within a 256-B row: element e -> lk*64 + kk*8 + j
static __device__ __forceinline__ int fragpos(int e) {
    return ((e >> 3) & 3) * 64 + (e >> 5) * 8 + (e & 7);
}

static __device__ __forceinline__ long long ll2(unsigned int a, unsigned int b) {
    return (long long)(((unsigned long long)b << 32) | a);
}

static __device__ __forceinline__ void gload_lds16(const void* g, void* l) {
    __builtin_amdgcn_global_load_lds((const __attribute__((address_space(1))) void*)g,
                                     (__attribute__((address_space(3))) void*)l,
                                     16, 0, 0);
}

template<int CTRL>
static __device__ __forceinline__ float dpp_add(float v) {
    int i = __builtin_amdgcn_update_dpp(0, __builtin_bit_cast(int, v), CTRL, 0xF, 0xF, false);
    return v + __builtin_bit_cast(float, i);
}
static __device__ __forceinline__ float row16_sum(float v) {
    v = dpp_add<0x121>(v);
    v = dpp_add<0x122>(v);
    v = dpp_add<0x124>(v);
    v = dpp_add<0x128>(v);
    return v;
}

// ---------------------------------------------------------------------------
// Kernel 0: vocab_w transpose -> frag-major fp8 (now standalone, x1).
// ---------------------------------------------------------------------------
__global__ __launch_bounds__(512) void transpose_kernel(const float* __restrict__ w,
                                                        unsigned char* __restrict__ wt8) {
    __shared__ float tile[64][65];
    const int tid = threadIdx.x;
    const int bb = blockIdx.x;           // 0..1999
    const int k0 = (bb & 3) * 64;
    const int n0 = (bb >> 2) * 64;
    const int c  = tid & 63;
    const int r8 = tid >> 6;
    #pragma unroll
    for (int r = r8; r < 64; r += 8)
        tile[r][c] = w[(size_t)(k0 + r) * V + n0 + c];
    __syncthreads();
    const int fp = fragpos(k0 + c);
    #pragma unroll
    for (int r = r8; r < 64; r += 8)
        wt8[(size_t)(n0 + r) * E + fp] = f2fp8(tile[c][r]);
}

// ---------------------------------------------------------------------------
// Kernel 1: RNN trajectory (x TREP identical repeats for measurement).
// ---------------------------------------------------------------------------
__global__ __launch_bounds__(512, 2) void traj_kernel(const float* __restrict__ latent,
                                                      const int* __restrict__ zi,
                                                      unsigned char* __restrict__ zsb8) {
    __shared__ __align__(16) short zsh[2][E];
    __shared__ __align__(16) float red[2][16];

    const int tid  = threadIdx.x;
    const int b    = blockIdx.x;
    const int lane = tid & 63;
    const int wv   = tid >> 6;
    const int lm   = lane & 15;
    const int g    = lane >> 4;
    const float* tr = latent + (size_t)zi[b] * (E * E);

    s16x8 bfrag[2][8];
    #pragma unroll
    for (int nt = 0; nt < 2; ++nt)
        #pragma unroll
        for (int kk = 0; kk < 8; ++kk) {
            s16x8 fr;
            #pragma unroll
            for (int j = 0; j < 8; ++j)
                fr[j] = f2bf(tr[(size_t)(kk * 32 + g * 8 + j) * E + wv * 32 + nt * 16 + lm]);
            bfrag[nt][kk] = fr;
        }

    const int p0i = fragpos(wv * 32 + lm);
    const int p1i = fragpos(wv * 32 + 16 + lm);

    for (int rep = 0; rep < TREP; ++rep) {
        __syncthreads();   // prior rep's last reads of zsh/red complete

        if (tid < E) zsh[0][tid] = f2bf(tr[tid]);
        {
            float v = (tid < E) ? tr[tid] : 0.f;
            float a = row16_sum(v), a2 = row16_sum(v * v);
            a  += __shfl_xor(a, 16);  a2 += __shfl_xor(a2, 16);
            a  += __shfl_xor(a, 32);  a2 += __shfl_xor(a2, 32);
            if (lane == 0) { red[1][wv] = a; red[1][8 + wv] = a2; }
        }
        __syncthreads();

        float scale;
        {
            f32x4 p0 = *(const f32x4*)&red[1][0], p1 = *(const f32x4*)&red[1][4];
            f32x4 q0 = *(const f32x4*)&red[1][8], q1 = *(const f32x4*)&red[1][12];
            float ts  = (p0[0]+p0[1]+p0[2]+p0[3]) + (p1[0]+p1[1]+p1[2]+p1[3]);
            float ts2 = (q0[0]+q0[1]+q0[2]+q0[3]) + (q1[0]+q1[1]+q1[2]+q1[3]);
            float var = fmaxf((ts2 - ts * ts * (1.0f / 256.0f)) * (1.0f / 255.0f), 0.f);
            scale = 0.113f / (1e-5f + sqrtf(var));
        }

        for (int t = 0; t < NSTEP; ++t) {
            const short* zrd = zsh[t & 1];
            s16x8 a[8];
            #pragma unroll
            for (int kk = 0; kk < 8; ++kk)
                a[kk] = *(const s16x8*)((const char*)zrd + kk * 64 + g * 16);

            f32x4 acc0 = {}, acc1 = {};
            #pragma unroll
            for (int kk = 0; kk < 8; ++kk) {
                acc0 = __builtin_amdgcn_mfma_f32_16x16x32_bf16(a[kk], bfrag[0][kk], acc0, 0, 0, 0);
                acc1 = __builtin_amdgcn_mfma_f32_16x16x32_bf16(a[kk], bfrag[1][kk], acc1, 0, 0, 0);
            }

            const float e0 = scale * acc0[0], e1 = scale * acc1[0];
            if (g == 0) {
                zsh[(t + 1) & 1][wv * 32 + lm]      = f2bf(e0);
                zsh[(t + 1) & 1][wv * 32 + 16 + lm] = f2bf(e1);
                unsigned char* zr = zsb8 + ((size_t)b * NSTEP + t) * E;
                zr[p0i] = f2fp8(e0);
                zr[p1i] = f2fp8(e1);
            }

            float u  = row16_sum(acc0[0] + acc1[0]);
            float u2 = row16_sum(acc0[0] * acc0[0] + acc1[0] * acc1[0]);
            if (lane == 0) { red[t & 1][wv] = u; red[t & 1][8 + wv] = u2; }
            __syncthreads();

            const float* rd = red[t & 1];
            f32x4 r0 = *(const f32x4*)&rd[0], r1 = *(const f32x4*)&rd[4];
            f32x4 s0 = *(const f32x4*)&rd[8], s1 = *(const f32x4*)&rd[12];
            float ts  = (r0[0]+r0[1]+r0[2]+r0[3]) + (r1[0]+r1[1]+r1[2]+r1[3]);
            float ts2 = (s0[0]+s0[1]+s0[2]+s0[3]) + (s1[0]+s1[1]+s1[2]+s1[3]);
            float var = fmaxf((ts2 - ts * ts * (1.0f / 256.0f)) * (1.0f / 255.0f), 0.f);
            scale = 0.113f / (1e-5f + scale * sqrtf(var));
        }
    }
}

// ---------------------------------------------------------------------------
// Kernel 2: persistent fp8 GEMM (x GREP identical repeats; rs scaled 1/GREP).
// ---------------------------------------------------------------------------
__global__ __launch_bounds__(512, 2) void gemm_lse_kernel(const unsigned char* __restrict__ zsb8,
                                                          const unsigned char* __restrict__ wt8,
                                                          const float* __restrict__ vb,
                                                          float* __restrict__ partial) {
    __shared__ unsigned char bpan0[BN2 * E];    // 32 KB
    __shared__ unsigned char bpan1[BN2 * E];    // 32 KB

    const int tid  = threadIdx.x;
    const int lane = tid & 63;
    const int w    = tid >> 6;         // 0..7
    const int grp  = blockIdx.x & 7;
    const int bm   = blockIdx.x >> 3;  // 0..31
    const int m0   = bm * BM;
    const int t0   = (NBT * grp) >> 3;
    const int t1   = (NBT * (grp + 1)) >> 3;

    const int wr = w >> 2, wc = w & 3;
    const int lm = lane & 15, lk = lane >> 4;
    const int mw = m0 + wr * 64;

    long long areg[4][8];
    #pragma unroll
    for (int rt = 0; rt < 4; ++rt)
        #pragma unroll
        for (int kp = 0; kp < 4; ++kp) {
            u32x4 v = *(const u32x4*)(zsb8 + (size_t)(mw + rt * 16 + lm) * E + lk * 64 + kp * 16);
            areg[rt][2 * kp]     = ll2(v[0], v[1]);
            areg[rt][2 * kp + 1] = ll2(v[2], v[3]);
        }

    float rs[4][4] = {};

    auto STAGE = [&](int tile, unsigned char* dst) {
        const size_t gbase = (size_t)(tile * BN2) * E;
        #pragma unroll
        for (int j = 0; j < 4; ++j) {
            const int c   = j * 512 + tid;
            const int row = c >> 4;
            const int gsl = ((c & 15) - row) & 15;
            gload_lds16(wt8 + gbase + (size_t)row * E + gsl * 16, dst + c * 16);
        }
    };

    auto COMPUTE = [&](const unsigned char* bp, f32x4 (&acc)[4][2], float (&bias)[2], int tile) {
        const int n0 = tile * BN2;
        bias[0] = vb[n0 + wc * 32 + lm] * L2E;
        bias[1] = vb[n0 + wc * 32 + 16 + lm] * L2E;
        #pragma unroll
        for (int rt = 0; rt < 4; ++rt) { acc[rt][0] = (f32x4){}; acc[rt][1] = (f32x4){}; }
        #pragma unroll
        for (int kp = 0; kp < 4; ++kp) {
            long long blo[2], bhi[2];
            #pragma unroll
            for (int nt = 0; nt < 2; ++nt) {
                const int rn   = wc * 32 + nt * 16 + lm;
                const int slot = (lk * 4 + kp + rn) & 15;
                u32x4 bv = *(const u32x4*)(bp + rn * 256 + slot * 16);
                blo[nt] = ll2(bv[0], bv[1]);
                bhi[nt] = ll2(bv[2], bv[3]);
            }
            #pragma unroll
            for (int rt = 0; rt < 4; ++rt) {
                acc[rt][0] = __builtin_amdgcn_mfma_f32_16x16x32_fp8_fp8(areg[rt][2 * kp], blo[0], acc[rt][0], 0, 0, 0);
                acc[rt][1] = __builtin_amdgcn_mfma_f32_16x16x32_fp8_fp8(areg[rt][2 * kp], blo[1], acc[rt][1], 0, 0, 0);
            }
            #pragma unroll
            for (int rt = 0; rt < 4; ++rt) {
                acc[rt][0] = __builtin_amdgcn_mfma_f32_16x16x32_fp8_fp8(areg[rt][2 * kp + 1], bhi[0], acc[rt][0], 0, 0, 0);
                acc[rt][1] = __builtin_amdgcn_mfma_f32_16x16x32_fp8_fp8(areg[rt][2 * kp + 1], bhi[1], acc[rt][1], 0, 0, 0);
            }
        }
    };

    auto EPI = [&](const f32x4 (&acc)[4][2], const float (&bias)[2]) {
        #pragma unroll
        for (int rt = 0; rt < 4; ++rt)
            #pragma unroll
            for (int r = 0; r < 4; ++r)
                rs[rt][r] += __builtin_amdgcn_exp2f(acc[rt][0][r] * L2E + bias[0])
                           + __builtin_amdgcn_exp2f(acc[rt][1][r] * L2E + bias[1]);
    };

    f32x4 accA[4][2], accB[4][2];
    float biasA[2], biasB[2];

    for (int rep = 0; rep < GREP; ++rep) {
        STAGE(t0, bpan0);
        __syncthreads();
        if (t0 + 1 < t1) STAGE(t0 + 1, bpan1);
        COMPUTE(bpan0, accA, biasA, t0);
        __syncthreads();

        int i = t0 + 1;
        bool lastA = true;
        while (i < t1) {
            {
                const unsigned char* bp = ((i - t0) & 1) ? bpan1 : bpan0;
                unsigned char*       st = ((i - t0) & 1) ? bpan0 : bpan1;
                if (i + 1 < t1) STAGE(i + 1, st);
                COMPUTE(bp, accB, biasB, i);
                EPI(accA, biasA);
                __syncthreads();
                lastA = false; ++i;
                if (i >= t1) break;
            }
            {
                const unsigned char* bp = ((i - t0) & 1) ? bpan1 : bpan0;
                unsigned char*       st = ((i - t0) & 1) ? bpan0 : bpan1;
                if (i + 1 < t1) STAGE(i + 1, st);
                COMPUTE(bp, accA, biasA, i);
                EPI(accB, biasB);
                __syncthreads();
                lastA = true; ++i;
            }
        }
        if (lastA) EPI(accA, biasA); else EPI(accB, biasB);
    }

    const int cr = lane >> 4;
    #pragma unroll
    for (int rt = 0; rt < 4; ++rt)
        #pragma unroll
        for (int r = 0; r < 4; ++r) {
            const float v = row16_sum(rs[rt][r] * (1.0f / GREP));
            if (lm == 0)
                partial[(size_t)(grp * 4 + wc) * M_TOTAL + mw + rt * 16 + cr * 4 + r] = v;
        }
}

// ---------------------------------------------------------------------------
// Kernel 3: finalize (unchanged).
// ---------------------------------------------------------------------------
__global__ __launch_bounds__(256) void finalize_kernel(const unsigned char* __restrict__ zsb8,
                                                       const unsigned char* __restrict__ wt8,
                                                       const float* __restrict__ vb,
                                                       const int* __restrict__ y,
                                                       const float* __restrict__ partial,
                                                       float* __restrict__ out) {
    const int tid  = threadIdx.x;
    const int lane = tid & 63;
    const int rw   = lane >> 4;
    const int kl   = lane & 15;
    const int row  = blockIdx.x * 16 + (tid >> 6) * 4 + rw;
    const int yrow = y[row];

    u32x4 za = *(const u32x4*)(zsb8 + (size_t)row * E + kl * 16);
    u32x4 wa = *(const u32x4*)(wt8 + (size_t)yrow * E + kl * 16);
    float acc = 0.f;
    #pragma unroll
    for (int q = 0; q < 4; ++q) {
        f32x2 a0 = fp8x2_to_f32<false>(za[q]), b0 = fp8x2_to_f32<false>(wa[q]);
        f32x2 a1 = fp8x2_to_f32<true>(za[q]),  b1 = fp8x2_to_f32<true>(wa[q]);
        acc += a0[0] * b0[0] + a0[1] * b0[1] + a1[0] * b1[0] + a1[1] * b1[1];
    }
    const float logit = row16_sum(acc) + vb[yrow];

    float ps = partial[(size_t)kl * M_TOTAL + row] + partial[(size_t)(kl + 16) * M_TOTAL + row];
    const float tot = row16_sum(ps);

    if (kl == 0) out[row] = logit - logf(tot);
}

// ---------------------------------------------------------------------------
extern "C" void kernel_launch(void* const* d_in, const int* in_sizes, int n_in,
                              void* d_out, int out_size, void* d_ws, size_t ws_size,
                              hipStream_t stream) {
    const float* latent  = (const float*)d_in[0];
    const float* vocab_w = (const float*)d_in[1];
    const float* vocab_b = (const float*)d_in[2];
    const int*   zi      = (const int*)d_in[3];
    const int*   y       = (const int*)d_in[4];
    float* out = (float*)d_out;

    char* ws = (char*)d_ws;
    float*         partial = (float*)(ws);                             // 512 KB
    unsigned char* zsb8    = (unsigned char*)(ws + 524288);            // 1 MB
    unsigned char* wt8     = (unsigned char*)(ws + 524288 + 1048576);  // 8 MB

    hipLaunchKernelGGL(transpose_kernel, dim3(4 * (V / 64)), dim3(512), 0, stream, vocab_w, wt8);
    hipLaunchKernelGGL(traj_kernel, dim3(BATCH), dim3(512), 0, stream, latent, zi, zsb8);
    hipLaunchKernelGGL(gemm_lse_kernel, dim3(32 * NGRP), dim3(512), 0, stream,
                       zsb8, wt8, vocab_b, partial);
    hipLaunchKernelGGL(finalize_kernel, dim3(M_TOTAL / 16), dim3(256), 0, stream,
                       zsb8, wt8, vocab_b, y, partial, out);
}

// Round 13
// 145.298 us; speedup vs baseline: 14.3775x; 14.3775x over previous
//
#include <hip/hip_runtime.h>
#include <hip/hip_bf16.h>

#define BATCH 32
#define E 256
#define V 32000
#define NSTEP 128
#define M_TOTAL (BATCH * NSTEP)   // 4096
#define BM 128
#define BN2 128
#define NBT (V / BN2)             // 250 b-tiles
#define NGRP 8                    // bn groups (== XCDs)
#define L2E 1.4426950408889634f

typedef __attribute__((ext_vector_type(4))) float f32x4;
typedef __attribute__((ext_vector_type(2))) float f32x2;
typedef __attribute__((ext_vector_type(8))) short s16x8;
typedef __attribute__((ext_vector_type(4))) unsigned int u32x4;

static __device__ __forceinline__ short f2bf(float v) {
    __hip_bfloat16 h = __float2bfloat16(v);
    return *reinterpret_cast<short*>(&h);
}

static __device__ __forceinline__ unsigned char f2fp8(float v) {
    int p = __builtin_amdgcn_cvt_pk_fp8_f32(v, v, 0, false);
    return (unsigned char)(p & 0xff);
}
template<bool HI>
static __device__ __forceinline__ f32x2 fp8x2_to_f32(unsigned int x) {
    return __builtin_amdgcn_cvt_pk_f32_fp8((int)x, HI);
}

// frag-major byte position within a 256-B row: element e -> lk*64 + kk*8 + j
static __device__ __forceinline__ int fragpos(int e) {
    return ((e >> 3) & 3) * 64 + (e >> 5) * 8 + (e & 7);
}

static __device__ __forceinline__ long long ll2(unsigned int a, unsigned int b) {
    return (long long)(((unsigned long long)b << 32) | a);
}

static __device__ __forceinline__ void gload_lds16(const void* g, void* l) {
    __builtin_amdgcn_global_load_lds((const __attribute__((address_space(1))) void*)g,
                                     (__attribute__((address_space(3))) void*)l,
                                     16, 0, 0);
}

template<int CTRL>
static __device__ __forceinline__ float dpp_add(float v) {
    int i = __builtin_amdgcn_update_dpp(0, __builtin_bit_cast(int, v), CTRL, 0xF, 0xF, false);
    return v + __builtin_bit_cast(float, i);
}
static __device__ __forceinline__ float row16_sum(float v) {
    v = dpp_add<0x121>(v);
    v = dpp_add<0x122>(v);
    v = dpp_add<0x124>(v);
    v = dpp_add<0x128>(v);
    return v;
}

// ---------------------------------------------------------------------------
// Kernel 1 (merged): blocks 0..31 = RNN trajectory; blocks 32.. = vocab_w
// transpose -> frag-major fp8. Trajectory: one barrier/step, global stores
// register-buffered and flushed every 8 steps (vmcnt drain amortized 8x),
// MFMA dep-chain split in two.
// ---------------------------------------------------------------------------
__global__ __launch_bounds__(512, 2) void traj_transpose_kernel(
        const float* __restrict__ latent, const int* __restrict__ zi,
        const float* __restrict__ w,
        unsigned char* __restrict__ zsb8, unsigned char* __restrict__ wt8) {
    __shared__ float tile[64][65];              // transpose path
    __shared__ __align__(16) short zsh[2][E];   // traj: z bf16, double-buffered
    __shared__ __align__(16) float red[2][16];  // traj: per-wave partials, dbuf

    const int tid = threadIdx.x;

    if (blockIdx.x >= BATCH) {
        const int bb = blockIdx.x - BATCH;   // 0..1999
        const int k0 = (bb & 3) * 64;
        const int n0 = (bb >> 2) * 64;
        const int c  = tid & 63;
        const int r8 = tid >> 6;
        #pragma unroll
        for (int r = r8; r < 64; r += 8)
            tile[r][c] = w[(size_t)(k0 + r) * V + n0 + c];
        __syncthreads();
        const int fp = fragpos(k0 + c);
        #pragma unroll
        for (int r = r8; r < 64; r += 8)
            wt8[(size_t)(n0 + r) * E + fp] = f2fp8(tile[c][r]);
        return;
    }

    // ---- trajectory path: one batch per block, 8 waves ----
    const int b    = blockIdx.x;
    const int lane = tid & 63;
    const int wv   = tid >> 6;
    const int lm   = lane & 15;
    const int g    = lane >> 4;
    const float* tr = latent + (size_t)zi[b] * (E * E);

    s16x8 bfrag[2][8];
    #pragma unroll
    for (int nt = 0; nt < 2; ++nt)
        #pragma unroll
        for (int kk = 0; kk < 8; ++kk) {
            s16x8 fr;
            #pragma unroll
            for (int j = 0; j < 8; ++j)
                fr[j] = f2bf(tr[(size_t)(kk * 32 + g * 8 + j) * E + wv * 32 + nt * 16 + lm]);
            bfrag[nt][kk] = fr;
        }

    if (tid < E) zsh[0][tid] = f2bf(tr[tid]);

    {   // scale_0 from std(z0)
        float v = (tid < E) ? tr[tid] : 0.f;
        float a = row16_sum(v), a2 = row16_sum(v * v);
        a  += __shfl_xor(a, 16);  a2 += __shfl_xor(a2, 16);
        a  += __shfl_xor(a, 32);  a2 += __shfl_xor(a2, 32);
        if (lane == 0) { red[1][wv] = a; red[1][8 + wv] = a2; }
    }
    __syncthreads();

    float scale;
    {
        f32x4 p0 = *(const f32x4*)&red[1][0], p1 = *(const f32x4*)&red[1][4];
        f32x4 q0 = *(const f32x4*)&red[1][8], q1 = *(const f32x4*)&red[1][12];
        float ts  = (p0[0]+p0[1]+p0[2]+p0[3]) + (p1[0]+p1[1]+p1[2]+p1[3]);
        float ts2 = (q0[0]+q0[1]+q0[2]+q0[3]) + (q1[0]+q1[1]+q1[2]+q1[3]);
        float var = fmaxf((ts2 - ts * ts * (1.0f / 256.0f)) * (1.0f / 255.0f), 0.f);
        scale = 0.113f / (1e-5f + sqrtf(var));
    }

    const int p0i = fragpos(wv * 32 + lm);
    const int p1i = fragpos(wv * 32 + 16 + lm);

    for (int tb = 0; tb < NSTEP; tb += 8) {
        unsigned char eb0[8], eb1[8];   // static-indexed only -> registers

        #pragma unroll
        for (int s = 0; s < 8; ++s) {
            const int t = tb + s;
            const short* zrd = zsh[t & 1];
            s16x8 a[8];
            #pragma unroll
            for (int kk = 0; kk < 8; ++kk)
                a[kk] = *(const s16x8*)((const char*)zrd + kk * 64 + g * 16);

            // two independent MFMA chains per output tile (halved dep latency)
            f32x4 a0l = {}, a0h = {}, a1l = {}, a1h = {};
            #pragma unroll
            for (int kk = 0; kk < 4; ++kk) {
                a0l = __builtin_amdgcn_mfma_f32_16x16x32_bf16(a[kk], bfrag[0][kk], a0l, 0, 0, 0);
                a1l = __builtin_amdgcn_mfma_f32_16x16x32_bf16(a[kk], bfrag[1][kk], a1l, 0, 0, 0);
            }
            #pragma unroll
            for (int kk = 4; kk < 8; ++kk) {
                a0h = __builtin_amdgcn_mfma_f32_16x16x32_bf16(a[kk], bfrag[0][kk], a0h, 0, 0, 0);
                a1h = __builtin_amdgcn_mfma_f32_16x16x32_bf16(a[kk], bfrag[1][kk], a1h, 0, 0, 0);
            }
            const float r0 = a0l[0] + a0h[0];
            const float r1 = a1l[0] + a1h[0];

            const float e0 = scale * r0, e1 = scale * r1;
            if (g == 0) {
                zsh[(t + 1) & 1][wv * 32 + lm]      = f2bf(e0);
                zsh[(t + 1) & 1][wv * 32 + 16 + lm] = f2bf(e1);
                eb0[s] = f2fp8(e0);
                eb1[s] = f2fp8(e1);
            }

            float u  = row16_sum(r0 + r1);
            float u2 = row16_sum(r0 * r0 + r1 * r1);
            if (lane == 0) { red[t & 1][wv] = u; red[t & 1][8 + wv] = u2; }
            __syncthreads();

            const float* rd = red[t & 1];
            f32x4 q0 = *(const f32x4*)&rd[0], q1 = *(const f32x4*)&rd[4];
            f32x4 v0 = *(const f32x4*)&rd[8], v1 = *(const f32x4*)&rd[12];
            float ts  = (q0[0]+q0[1]+q0[2]+q0[3]) + (q1[0]+q1[1]+q1[2]+q1[3]);
            float ts2 = (v0[0]+v0[1]+v0[2]+v0[3]) + (v1[0]+v1[1]+v1[2]+v1[3]);
            float var = fmaxf((ts2 - ts * ts * (1.0f / 256.0f)) * (1.0f / 255.0f), 0.f);
            scale = 0.113f / (1e-5f + scale * sqrtf(var));
        }

        // ---- flush: 16 byte-stores, drained once at the next barrier ----
        if (g == 0) {
            unsigned char* zr = zsb8 + ((size_t)b * NSTEP + tb) * E;
            #pragma unroll
            for (int s = 0; s < 8; ++s) {
                zr[s * E + p0i] = eb0[s];
                zr[s * E + p1i] = eb1[s];
            }
        }
    }
}

// ---------------------------------------------------------------------------
// Kernel 2: persistent fp8 GEMM, 2-deep acc pipeline (single-pass, R11 form).
// ---------------------------------------------------------------------------
__global__ __launch_bounds__(512, 2) void gemm_lse_kernel(const unsigned char* __restrict__ zsb8,
                                                          const unsigned char* __restrict__ wt8,
                                                          const float* __restrict__ vb,
                                                          float* __restrict__ partial) {
    __shared__ unsigned char bpan0[BN2 * E];    // 32 KB
    __shared__ unsigned char bpan1[BN2 * E];    // 32 KB

    const int tid  = threadIdx.x;
    const int lane = tid & 63;
    const int w    = tid >> 6;         // 0..7
    const int grp  = blockIdx.x & 7;
    const int bm   = blockIdx.x >> 3;  // 0..31
    const int m0   = bm * BM;
    const int t0   = (NBT * grp) >> 3;
    const int t1   = (NBT * (grp + 1)) >> 3;

    const int wr = w >> 2, wc = w & 3;
    const int lm = lane & 15, lk = lane >> 4;
    const int mw = m0 + wr * 64;

    long long areg[4][8];
    #pragma unroll
    for (int rt = 0; rt < 4; ++rt)
        #pragma unroll
        for (int kp = 0; kp < 4; ++kp) {
            u32x4 v = *(const u32x4*)(zsb8 + (size_t)(mw + rt * 16 + lm) * E + lk * 64 + kp * 16);
            areg[rt][2 * kp]     = ll2(v[0], v[1]);
            areg[rt][2 * kp + 1] = ll2(v[2], v[3]);
        }

    float rs[4][4] = {};

    auto STAGE = [&](int tile, unsigned char* dst) {
        const size_t gbase = (size_t)(tile * BN2) * E;
        #pragma unroll
        for (int j = 0; j < 4; ++j) {
            const int c   = j * 512 + tid;
            const int row = c >> 4;
            const int gsl = ((c & 15) - row) & 15;
            gload_lds16(wt8 + gbase + (size_t)row * E + gsl * 16, dst + c * 16);
        }
    };

    auto COMPUTE = [&](const unsigned char* bp, f32x4 (&acc)[4][2], float (&bias)[2], int tile) {
        const int n0 = tile * BN2;
        bias[0] = vb[n0 + wc * 32 + lm] * L2E;
        bias[1] = vb[n0 + wc * 32 + 16 + lm] * L2E;
        #pragma unroll
        for (int rt = 0; rt < 4; ++rt) { acc[rt][0] = (f32x4){}; acc[rt][1] = (f32x4){}; }
        #pragma unroll
        for (int kp = 0; kp < 4; ++kp) {
            long long blo[2], bhi[2];
            #pragma unroll
            for (int nt = 0; nt < 2; ++nt) {
                const int rn   = wc * 32 + nt * 16 + lm;
                const int slot = (lk * 4 + kp + rn) & 15;
                u32x4 bv = *(const u32x4*)(bp + rn * 256 + slot * 16);
                blo[nt] = ll2(bv[0], bv[1]);
                bhi[nt] = ll2(bv[2], bv[3]);
            }
            #pragma unroll
            for (int rt = 0; rt < 4; ++rt) {
                acc[rt][0] = __builtin_amdgcn_mfma_f32_16x16x32_fp8_fp8(areg[rt][2 * kp], blo[0], acc[rt][0], 0, 0, 0);
                acc[rt][1] = __builtin_amdgcn_mfma_f32_16x16x32_fp8_fp8(areg[rt][2 * kp], blo[1], acc[rt][1], 0, 0, 0);
            }
            #pragma unroll
            for (int rt = 0; rt < 4; ++rt) {
                acc[rt][0] = __builtin_amdgcn_mfma_f32_16x16x32_fp8_fp8(areg[rt][2 * kp + 1], bhi[0], acc[rt][0], 0, 0, 0);
                acc[rt][1] = __builtin_amdgcn_mfma_f32_16x16x32_fp8_fp8(areg[rt][2 * kp + 1], bhi[1], acc[rt][1], 0, 0, 0);
            }
        }
    };

    auto EPI = [&](const f32x4 (&acc)[4][2], const float (&bias)[2]) {
        #pragma unroll
        for (int rt = 0; rt < 4; ++rt)
            #pragma unroll
            for (int r = 0; r < 4; ++r)
                rs[rt][r] += __builtin_amdgcn_exp2f(acc[rt][0][r] * L2E + bias[0])
                           + __builtin_amdgcn_exp2f(acc[rt][1][r] * L2E + bias[1]);
    };

    f32x4 accA[4][2], accB[4][2];
    float biasA[2], biasB[2];

    STAGE(t0, bpan0);
    __syncthreads();
    if (t0 + 1 < t1) STAGE(t0 + 1, bpan1);
    COMPUTE(bpan0, accA, biasA, t0);
    __syncthreads();

    int i = t0 + 1;
    bool lastA = true;
    while (i < t1) {
        {
            const unsigned char* bp = ((i - t0) & 1) ? bpan1 : bpan0;
            unsigned char*       st = ((i - t0) & 1) ? bpan0 : bpan1;
            if (i + 1 < t1) STAGE(i + 1, st);
            COMPUTE(bp, accB, biasB, i);
            EPI(accA, biasA);
            __syncthreads();
            lastA = false; ++i;
            if (i >= t1) break;
        }
        {
            const unsigned char* bp = ((i - t0) & 1) ? bpan1 : bpan0;
            unsigned char*       st = ((i - t0) & 1) ? bpan0 : bpan1;
            if (i + 1 < t1) STAGE(i + 1, st);
            COMPUTE(bp, accA, biasA, i);
            EPI(accB, biasB);
            __syncthreads();
            lastA = true; ++i;
        }
    }
    if (lastA) EPI(accA, biasA); else EPI(accB, biasB);

    const int cr = lane >> 4;
    #pragma unroll
    for (int rt = 0; rt < 4; ++rt)
        #pragma unroll
        for (int r = 0; r < 4; ++r) {
            const float v = row16_sum(rs[rt][r]);
            if (lm == 0)
                partial[(size_t)(grp * 4 + wc) * M_TOTAL + mw + rt * 16 + cr * 4 + r] = v;
        }
}

// ---------------------------------------------------------------------------
// Kernel 3: finalize (unchanged).
// ---------------------------------------------------------------------------
__global__ __launch_bounds__(256) void finalize_kernel(const unsigned char* __restrict__ zsb8,
                                                       const unsigned char* __restrict__ wt8,
                                                       const float* __restrict__ vb,
                                                       const int* __restrict__ y,
                                                       const float* __restrict__ partial,
                                                       float* __restrict__ out) {
    const int tid  = threadIdx.x;
    const int lane = tid & 63;
    const int rw   = lane >> 4;
    const int kl   = lane & 15;
    const int row  = blockIdx.x * 16 + (tid >> 6) * 4 + rw;
    const int yrow = y[row];

    u32x4 za = *(const u32x4*)(zsb8 + (size_t)row * E + kl * 16);
    u32x4 wa = *(const u32x4*)(wt8 + (size_t)yrow * E + kl * 16);
    float acc = 0.f;
    #pragma unroll
    for (int q = 0; q < 4; ++q) {
        f32x2 a0 = fp8x2_to_f32<false>(za[q]), b0 = fp8x2_to_f32<false>(wa[q]);
        f32x2 a1 = fp8x2_to_f32<true>(za[q]),  b1 = fp8x2_to_f32<true>(wa[q]);
        acc += a0[0] * b0[0] + a0[1] * b0[1] + a1[0] * b1[0] + a1[1] * b1[1];
    }
    const float logit = row16_sum(acc) + vb[yrow];

    float ps = partial[(size_t)kl * M_TOTAL + row] + partial[(size_t)(kl + 16) * M_TOTAL + row];
    const float tot = row16_sum(ps);

    if (kl == 0) out[row] = logit - logf(tot);
}

// ---------------------------------------------------------------------------
extern "C" void kernel_launch(void* const* d_in, const int* in_sizes, int n_in,
                              void* d_out, int out_size, void* d_ws, size_t ws_size,
                              hipStream_t stream) {
    const float* latent  = (const float*)d_in[0];
    const float* vocab_w = (const float*)d_in[1];
    const float* vocab_b = (const float*)d_in[2];
    const int*   zi      = (const int*)d_in[3];
    const int*   y       = (const int*)d_in[4];
    float* out = (float*)d_out;

    char* ws = (char*)d_ws;
    float*         partial = (float*)(ws);                             // 512 KB
    unsigned char* zsb8    = (unsigned char*)(ws + 524288);            // 1 MB
    unsigned char* wt8     = (unsigned char*)(ws + 524288 + 1048576);  // 8 MB

    hipLaunchKernelGGL(traj_transpose_kernel, dim3(BATCH + 4 * (V / 64)), dim3(512), 0, stream,
                       latent, zi, vocab_w, zsb8, wt8);
    hipLaunchKernelGGL(gemm_lse_kernel, dim3(32 * NGRP), dim3(512), 0, stream,
                       zsb8, wt8, vocab_b, partial);
    hipLaunchKernelGGL(finalize_kernel, dim3(M_TOTAL / 16), dim3(256), 0, stream,
                       zsb8, wt8, vocab_b, y, partial, out);
}

// Round 14
// 143.998 us; speedup vs baseline: 14.5074x; 1.0090x over previous
//
#include <hip/hip_runtime.h>
#include <hip/hip_bf16.h>

#define BATCH 32
#define E 256
#define V 32000
#define NSTEP 128
#define M_TOTAL (BATCH * NSTEP)   // 4096
#define BM 128
#define BN2 128
#define NBT (V / BN2)             // 250 b-tiles
#define NGRP 8                    // bn groups (== XCDs)
#define L2E 1.4426950408889634f

typedef __attribute__((ext_vector_type(4))) float f32x4;
typedef __attribute__((ext_vector_type(2))) float f32x2;
typedef __attribute__((ext_vector_type(8))) short s16x8;
typedef __attribute__((ext_vector_type(4))) unsigned int u32x4;

static __device__ __forceinline__ short f2bf(float v) {
    __hip_bfloat16 h = __float2bfloat16(v);
    return *reinterpret_cast<short*>(&h);
}

static __device__ __forceinline__ unsigned char f2fp8(float v) {
    int p = __builtin_amdgcn_cvt_pk_fp8_f32(v, v, 0, false);
    return (unsigned char)(p & 0xff);
}
template<bool HI>
static __device__ __forceinline__ f32x2 fp8x2_to_f32(unsigned int x) {
    return __builtin_amdgcn_cvt_pk_f32_fp8((int)x, HI);
}

// frag-major byte position within a 256-B row: element e -> lk*64 + kk*8 + j
static __device__ __forceinline__ int fragpos(int e) {
    return ((e >> 3) & 3) * 64 + (e >> 5) * 8 + (e & 7);
}

static __device__ __forceinline__ long long ll2(unsigned int a, unsigned int b) {
    return (long long)(((unsigned long long)b << 32) | a);
}

static __device__ __forceinline__ void gload_lds16(const void* g, void* l) {
    __builtin_amdgcn_global_load_lds((const __attribute__((address_space(1))) void*)g,
                                     (__attribute__((address_space(3))) void*)l,
                                     16, 0, 0);
}

template<int CTRL>
static __device__ __forceinline__ float dpp_add(float v) {
    int i = __builtin_amdgcn_update_dpp(0, __builtin_bit_cast(int, v), CTRL, 0xF, 0xF, false);
    return v + __builtin_bit_cast(float, i);
}
static __device__ __forceinline__ float row16_sum(float v) {
    v = dpp_add<0x121>(v);
    v = dpp_add<0x122>(v);
    v = dpp_add<0x124>(v);
    v = dpp_add<0x128>(v);
    return v;
}

// ---------------------------------------------------------------------------
// Kernel 1 (merged): blocks 0..31 = RNN trajectory; blocks 32.. = vocab_w
// transpose -> frag-major fp8.
// Trajectory: LDS carries the UNSCALED iterate u (u_{s+1} = scale_{s-1} *
// W^T u_s) so the std/scale computation is one step behind and entirely off
// the critical path. One barrier/step; emits register-buffered, flushed
// every 8 steps.
// ---------------------------------------------------------------------------
__global__ __launch_bounds__(512, 2) void traj_transpose_kernel(
        const float* __restrict__ latent, const int* __restrict__ zi,
        const float* __restrict__ w,
        unsigned char* __restrict__ zsb8, unsigned char* __restrict__ wt8) {
    __shared__ float tile[64][65];              // transpose path
    __shared__ __align__(16) short zsh[2][E];   // traj: û (unscaled), dbuf
    __shared__ __align__(16) float red[2][16];  // traj: u-stats partials, dbuf

    const int tid = threadIdx.x;

    if (blockIdx.x >= BATCH) {
        const int bb = blockIdx.x - BATCH;   // 0..1999
        const int k0 = (bb & 3) * 64;
        const int n0 = (bb >> 2) * 64;
        const int c  = tid & 63;
        const int r8 = tid >> 6;
        #pragma unroll
        for (int r = r8; r < 64; r += 8)
            tile[r][c] = w[(size_t)(k0 + r) * V + n0 + c];
        __syncthreads();
        const int fp = fragpos(k0 + c);
        #pragma unroll
        for (int r = r8; r < 64; r += 8)
            wt8[(size_t)(n0 + r) * E + fp] = f2fp8(tile[c][r]);
        return;
    }

    // ---- trajectory path: one batch per block, 8 waves ----
    const int b    = blockIdx.x;
    const int lane = tid & 63;
    const int wv   = tid >> 6;
    const int lm   = lane & 15;
    const int g    = lane >> 4;
    const float* tr = latent + (size_t)zi[b] * (E * E);

    s16x8 bfrag[2][8];
    #pragma unroll
    for (int nt = 0; nt < 2; ++nt)
        #pragma unroll
        for (int kk = 0; kk < 8; ++kk) {
            s16x8 fr;
            #pragma unroll
            for (int j = 0; j < 8; ++j)
                fr[j] = f2bf(tr[(size_t)(kk * 32 + g * 8 + j) * E + wv * 32 + nt * 16 + lm]);
            bfrag[nt][kk] = fr;
        }

    // û_0 = bf16(z_0) (u_0 = z_0, scale_{-1} = 1)
    if (tid < E) zsh[0][tid] = f2bf(tr[tid]);

    {   // stats of u_0 -> red[1] (step 0 reads red[(0+1)&1])
        float v = (tid < E) ? tr[tid] : 0.f;
        float a = row16_sum(v), a2 = row16_sum(v * v);
        a  += __shfl_xor(a, 16);  a2 += __shfl_xor(a2, 16);
        a  += __shfl_xor(a, 32);  a2 += __shfl_xor(a2, 32);
        if (lane == 0) { red[1][wv] = a; red[1][8 + wv] = a2; }
    }
    __syncthreads();

    float scale_prev = 1.0f;   // scale_{s-1}

    const int p0i = fragpos(wv * 32 + lm);
    const int p1i = fragpos(wv * 32 + 16 + lm);

    for (int tb = 0; tb < NSTEP; tb += 8) {
        unsigned char eb0[8], eb1[8];   // static-indexed only -> registers

        #pragma unroll
        for (int s = 0; s < 8; ++s) {
            const int t = tb + s;
            const short* zrd = zsh[t & 1];
            s16x8 a[8];
            #pragma unroll
            for (int kk = 0; kk < 8; ++kk)
                a[kk] = *(const s16x8*)((const char*)zrd + kk * 64 + g * 16);

            // scale_s from u_s stats (published at step s-1) -- off-path,
            // overlaps the MFMA chain below.
            const float* rd = red[(t + 1) & 1];
            f32x4 q0 = *(const f32x4*)&rd[0], q1 = *(const f32x4*)&rd[4];
            f32x4 v0 = *(const f32x4*)&rd[8], v1 = *(const f32x4*)&rd[12];
            float ts  = (q0[0]+q0[1]+q0[2]+q0[3]) + (q1[0]+q1[1]+q1[2]+q1[3]);
            float ts2 = (v0[0]+v0[1]+v0[2]+v0[3]) + (v1[0]+v1[1]+v1[2]+v1[3]);
            float var = fmaxf((ts2 - ts * ts * (1.0f / 256.0f)) * (1.0f / 255.0f), 0.f);
            const float scale_cur = 0.113f / (1e-5f + scale_prev * sqrtf(var));

            // m = W^T u_s  (two independent chains per tile)
            f32x4 a0l = {}, a0h = {}, a1l = {}, a1h = {};
            #pragma unroll
            for (int kk = 0; kk < 4; ++kk) {
                a0l = __builtin_amdgcn_mfma_f32_16x16x32_bf16(a[kk], bfrag[0][kk], a0l, 0, 0, 0);
                a1l = __builtin_amdgcn_mfma_f32_16x16x32_bf16(a[kk], bfrag[1][kk], a1l, 0, 0, 0);
            }
            #pragma unroll
            for (int kk = 4; kk < 8; ++kk) {
                a0h = __builtin_amdgcn_mfma_f32_16x16x32_bf16(a[kk], bfrag[0][kk], a0h, 0, 0, 0);
                a1h = __builtin_amdgcn_mfma_f32_16x16x32_bf16(a[kk], bfrag[1][kk], a1h, 0, 0, 0);
            }

            // u_{s+1} = scale_{s-1} * m ;  z_{s+1} = scale_s * u_{s+1}
            const float u0 = scale_prev * (a0l[0] + a0h[0]);
            const float u1 = scale_prev * (a1l[0] + a1h[0]);
            if (g == 0) {
                zsh[(t + 1) & 1][wv * 32 + lm]      = f2bf(u0);
                zsh[(t + 1) & 1][wv * 32 + 16 + lm] = f2bf(u1);
                eb0[s] = f2fp8(scale_cur * u0);
                eb1[s] = f2fp8(scale_cur * u1);
            }

            // stats of u_{s+1} for step s+1 (consumed one step later)
            float su  = row16_sum(u0 + u1);
            float su2 = row16_sum(u0 * u0 + u1 * u1);
            if (lane == 0) { red[t & 1][wv] = su; red[t & 1][8 + wv] = su2; }

            scale_prev = scale_cur;
            __syncthreads();
        }

        // ---- flush: 16 byte-stores, drained once at the next barrier ----
        if (g == 0) {
            unsigned char* zr = zsb8 + ((size_t)b * NSTEP + tb) * E;
            #pragma unroll
            for (int s = 0; s < 8; ++s) {
                zr[s * E + p0i] = eb0[s];
                zr[s * E + p1i] = eb1[s];
            }
        }
    }
}

// ---------------------------------------------------------------------------
// Kernel 2: persistent fp8 GEMM, 2-deep acc pipeline (unchanged).
// ---------------------------------------------------------------------------
__global__ __launch_bounds__(512, 2) void gemm_lse_kernel(const unsigned char* __restrict__ zsb8,
                                                          const unsigned char* __restrict__ wt8,
                                                          const float* __restrict__ vb,
                                                          float* __restrict__ partial) {
    __shared__ unsigned char bpan0[BN2 * E];    // 32 KB
    __shared__ unsigned char bpan1[BN2 * E];    // 32 KB

    const int tid  = threadIdx.x;
    const int lane = tid & 63;
    const int w    = tid >> 6;         // 0..7
    const int grp  = blockIdx.x & 7;
    const int bm   = blockIdx.x >> 3;  // 0..31
    const int m0   = bm * BM;
    const int t0   = (NBT * grp) >> 3;
    const int t1   = (NBT * (grp + 1)) >> 3;

    const int wr = w >> 2, wc = w & 3;
    const int lm = lane & 15, lk = lane >> 4;
    const int mw = m0 + wr * 64;

    long long areg[4][8];
    #pragma unroll
    for (int rt = 0; rt < 4; ++rt)
        #pragma unroll
        for (int kp = 0; kp < 4; ++kp) {
            u32x4 v = *(const u32x4*)(zsb8 + (size_t)(mw + rt * 16 + lm) * E + lk * 64 + kp * 16);
            areg[rt][2 * kp]     = ll2(v[0], v[1]);
            areg[rt][2 * kp + 1] = ll2(v[2], v[3]);
        }

    float rs[4][4] = {};

    auto STAGE = [&](int tile, unsigned char* dst) {
        const size_t gbase = (size_t)(tile * BN2) * E;
        #pragma unroll
        for (int j = 0; j < 4; ++j) {
            const int c   = j * 512 + tid;
            const int row = c >> 4;
            const int gsl = ((c & 15) - row) & 15;
            gload_lds16(wt8 + gbase + (size_t)row * E + gsl * 16, dst + c * 16);
        }
    };

    auto COMPUTE = [&](const unsigned char* bp, f32x4 (&acc)[4][2], float (&bias)[2], int tile) {
        const int n0 = tile * BN2;
        bias[0] = vb[n0 + wc * 32 + lm] * L2E;
        bias[1] = vb[n0 + wc * 32 + 16 + lm] * L2E;
        #pragma unroll
        for (int rt = 0; rt < 4; ++rt) { acc[rt][0] = (f32x4){}; acc[rt][1] = (f32x4){}; }
        #pragma unroll
        for (int kp = 0; kp < 4; ++kp) {
            long long blo[2], bhi[2];
            #pragma unroll
            for (int nt = 0; nt < 2; ++nt) {
                const int rn   = wc * 32 + nt * 16 + lm;
                const int slot = (lk * 4 + kp + rn) & 15;
                u32x4 bv = *(const u32x4*)(bp + rn * 256 + slot * 16);
                blo[nt] = ll2(bv[0], bv[1]);
                bhi[nt] = ll2(bv[2], bv[3]);
            }
            #pragma unroll
            for (int rt = 0; rt < 4; ++rt) {
                acc[rt][0] = __builtin_amdgcn_mfma_f32_16x16x32_fp8_fp8(areg[rt][2 * kp], blo[0], acc[rt][0], 0, 0, 0);
                acc[rt][1] = __builtin_amdgcn_mfma_f32_16x16x32_fp8_fp8(areg[rt][2 * kp], blo[1], acc[rt][1], 0, 0, 0);
            }
            #pragma unroll
            for (int rt = 0; rt < 4; ++rt) {
                acc[rt][0] = __builtin_amdgcn_mfma_f32_16x16x32_fp8_fp8(areg[rt][2 * kp + 1], bhi[0], acc[rt][0], 0, 0, 0);
                acc[rt][1] = __builtin_amdgcn_mfma_f32_16x16x32_fp8_fp8(areg[rt][2 * kp + 1], bhi[1], acc[rt][1], 0, 0, 0);
            }
        }
    };

    auto EPI = [&](const f32x4 (&acc)[4][2], const float (&bias)[2]) {
        #pragma unroll
        for (int rt = 0; rt < 4; ++rt)
            #pragma unroll
            for (int r = 0; r < 4; ++r)
                rs[rt][r] += __builtin_amdgcn_exp2f(acc[rt][0][r] * L2E + bias[0])
                           + __builtin_amdgcn_exp2f(acc[rt][1][r] * L2E + bias[1]);
    };

    f32x4 accA[4][2], accB[4][2];
    float biasA[2], biasB[2];

    STAGE(t0, bpan0);
    __syncthreads();
    if (t0 + 1 < t1) STAGE(t0 + 1, bpan1);
    COMPUTE(bpan0, accA, biasA, t0);
    __syncthreads();

    int i = t0 + 1;
    bool lastA = true;
    while (i < t1) {
        {
            const unsigned char* bp = ((i - t0) & 1) ? bpan1 : bpan0;
            unsigned char*       st = ((i - t0) & 1) ? bpan0 : bpan1;
            if (i + 1 < t1) STAGE(i + 1, st);
            COMPUTE(bp, accB, biasB, i);
            EPI(accA, biasA);
            __syncthreads();
            lastA = false; ++i;
            if (i >= t1) break;
        }
        {
            const unsigned char* bp = ((i - t0) & 1) ? bpan1 : bpan0;
            unsigned char*       st = ((i - t0) & 1) ? bpan0 : bpan1;
            if (i + 1 < t1) STAGE(i + 1, st);
            COMPUTE(bp, accA, biasA, i);
            EPI(accB, biasB);
            __syncthreads();
            lastA = true; ++i;
        }
    }
    if (lastA) EPI(accA, biasA); else EPI(accB, biasB);

    const int cr = lane >> 4;
    #pragma unroll
    for (int rt = 0; rt < 4; ++rt)
        #pragma unroll
        for (int r = 0; r < 4; ++r) {
            const float v = row16_sum(rs[rt][r]);
            if (lm == 0)
                partial[(size_t)(grp * 4 + wc) * M_TOTAL + mw + rt * 16 + cr * 4 + r] = v;
        }
}

// ---------------------------------------------------------------------------
// Kernel 3: finalize (unchanged).
// ---------------------------------------------------------------------------
__global__ __launch_bounds__(256) void finalize_kernel(const unsigned char* __restrict__ zsb8,
                                                       const unsigned char* __restrict__ wt8,
                                                       const float* __restrict__ vb,
                                                       const int* __restrict__ y,
                                                       const float* __restrict__ partial,
                                                       float* __restrict__ out) {
    const int tid  = threadIdx.x;
    const int lane = tid & 63;
    const int rw   = lane >> 4;
    const int kl   = lane & 15;
    const int row  = blockIdx.x * 16 + (tid >> 6) * 4 + rw;
    const int yrow = y[row];

    u32x4 za = *(const u32x4*)(zsb8 + (size_t)row * E + kl * 16);
    u32x4 wa = *(const u32x4*)(wt8 + (size_t)yrow * E + kl * 16);
    float acc = 0.f;
    #pragma unroll
    for (int q = 0; q < 4; ++q) {
        f32x2 a0 = fp8x2_to_f32<false>(za[q]), b0 = fp8x2_to_f32<false>(wa[q]);
        f32x2 a1 = fp8x2_to_f32<true>(za[q]),  b1 = fp8x2_to_f32<true>(wa[q]);
        acc += a0[0] * b0[0] + a0[1] * b0[1] + a1[0] * b1[0] + a1[1] * b1[1];
    }
    const float logit = row16_sum(acc) + vb[yrow];

    float ps = partial[(size_t)kl * M_TOTAL + row] + partial[(size_t)(kl + 16) * M_TOTAL + row];
    const float tot = row16_sum(ps);

    if (kl == 0) out[row] = logit - logf(tot);
}

// ---------------------------------------------------------------------------
extern "C" void kernel_launch(void* const* d_in, const int* in_sizes, int n_in,
                              void* d_out, int out_size, void* d_ws, size_t ws_size,
                              hipStream_t stream) {
    const float* latent  = (const float*)d_in[0];
    const float* vocab_w = (const float*)d_in[1];
    const float* vocab_b = (const float*)d_in[2];
    const int*   zi      = (const int*)d_in[3];
    const int*   y       = (const int*)d_in[4];
    float* out = (float*)d_out;

    char* ws = (char*)d_ws;
    float*         partial = (float*)(ws);                             // 512 KB
    unsigned char* zsb8    = (unsigned char*)(ws + 524288);            // 1 MB
    unsigned char* wt8     = (unsigned char*)(ws + 524288 + 1048576);  // 8 MB

    hipLaunchKernelGGL(traj_transpose_kernel, dim3(BATCH + 4 * (V / 64)), dim3(512), 0, stream,
                       latent, zi, vocab_w, zsb8, wt8);
    hipLaunchKernelGGL(gemm_lse_kernel, dim3(32 * NGRP), dim3(512), 0, stream,
                       zsb8, wt8, vocab_b, partial);
    hipLaunchKernelGGL(finalize_kernel, dim3(M_TOTAL / 16), dim3(256), 0, stream,
                       zsb8, wt8, vocab_b, y, partial, out);
}